// Round 1
// baseline (396.555 us; speedup 1.0000x reference)
//
#include <hip/hip_runtime.h>
#include <hip/hip_bf16.h>

#define DD 256
#define KC 1024

typedef __attribute__((ext_vector_type(4))) float f32x4;
typedef __attribute__((ext_vector_type(8))) short bf16x8;
typedef __attribute__((ext_vector_type(4))) short s16x4;

static __device__ __forceinline__ short f2bf(float f) {
    union { float f; unsigned u; } v; v.f = f;
    unsigned u = v.u;
    unsigned r = u + 0x7fffu + ((u >> 16) & 1u);
    return (short)(r >> 16);
}

// ---------------------------------------------------------------------------
// prep: W fp32 [1024][256] -> wbf bf16 [1024][256], wtbf bf16 [256][1024],
//       wsq[k] = sum_d W[k][d]^2 / 256
// ---------------------------------------------------------------------------
__global__ void prep_kernel(const float* __restrict__ w, short* __restrict__ wbf,
                            short* __restrict__ wtbf, float* __restrict__ wsq) {
    const int cod = blockIdx.x;
    const int d   = threadIdx.x;           // 256 threads
    float v = w[cod * DD + d];
    short b = f2bf(v);
    wbf[cod * DD + d] = b;
    wtbf[d * KC + cod] = b;
    float s = v * v;
    #pragma unroll
    for (int m = 32; m >= 1; m >>= 1) s += __shfl_xor(s, m, 64);
    __shared__ float ps[4];
    const int wave = threadIdx.x >> 6, lane = threadIdx.x & 63;
    if (lane == 0) ps[wave] = s;
    __syncthreads();
    if (threadIdx.x == 0) {
        wsq[cod] = (ps[0] + ps[1] + ps[2] + ps[3]) * (1.0f / (float)DD);
    }
}

// ---------------------------------------------------------------------------
// score kernel: per block, BM=32 rows x all 1024 codes.
// q[n][k] = exp(cross/128 - wsq) / rowsum   (x^2 term cancels in softmax)
// 8 waves, wave w owns codes [w*128, w*128+128).
// ---------------------------------------------------------------------------
#define BM 32
#define XLD 264   // 256 + 8 pad (bf16 elems); row stride 528 B (16B-aligned)

__global__ __launch_bounds__(512, 2) void score_kernel(
    const float* __restrict__ x, const short* __restrict__ wbf,
    const float* __restrict__ wsq, float* __restrict__ qdist) {
    __shared__ short xs[BM * XLD];
    __shared__ float red[8][BM];

    const int t    = threadIdx.x;
    const int wave = t >> 6;
    const int lane = t & 63;
    const int lhi  = lane >> 4, llo = lane & 15;
    const long rowbase = (long)blockIdx.x * BM;

    // stage x tile (32 x 256 fp32) -> bf16 LDS
    const f32x4* xv = (const f32x4*)(x + rowbase * DD);
    #pragma unroll
    for (int i = 0; i < 4; i++) {
        int f4 = t + i * 512;          // 0..2047 ; row = f4/64, col4 = f4%64
        f32x4 v = xv[f4];
        int row = f4 >> 6, c4 = f4 & 63;
        s16x4 sv;
        sv[0] = f2bf(v[0]); sv[1] = f2bf(v[1]); sv[2] = f2bf(v[2]); sv[3] = f2bf(v[3]);
        *(s16x4*)(xs + row * XLD + c4 * 4) = sv;
    }
    __syncthreads();

    const int cb = wave * 128;
    float e[8][2][4];
    float rs0[4] = {0.f, 0.f, 0.f, 0.f};
    float rs1[4] = {0.f, 0.f, 0.f, 0.f};

    #pragma unroll
    for (int ct = 0; ct < 8; ct++) {
        const int cod = cb + ct * 16 + llo;
        f32x4 acc0 = {0.f, 0.f, 0.f, 0.f};
        f32x4 acc1 = {0.f, 0.f, 0.f, 0.f};
        const short* wrow = wbf + (size_t)cod * DD + lhi * 8;
        const short* xr0  = xs + llo * XLD + lhi * 8;
        const short* xr1  = xr0 + 16 * XLD;
        #pragma unroll
        for (int kk = 0; kk < 8; kk++) {
            bf16x8 bf = *(const bf16x8*)(wrow + kk * 32);
            bf16x8 a0 = *(const bf16x8*)(xr0 + kk * 32);
            bf16x8 a1 = *(const bf16x8*)(xr1 + kk * 32);
            acc0 = __builtin_amdgcn_mfma_f32_16x16x32_bf16(a0, bf, acc0, 0, 0, 0);
            acc1 = __builtin_amdgcn_mfma_f32_16x16x32_bf16(a1, bf, acc1, 0, 0, 0);
        }
        const float ws = wsq[cod];
        #pragma unroll
        for (int r = 0; r < 4; r++) {
            float e0 = __expf(acc0[r] * (1.0f / 128.0f) - ws);
            float e1 = __expf(acc1[r] * (1.0f / 128.0f) - ws);
            e[ct][0][r] = e0; e[ct][1][r] = e1;
            rs0[r] += e0;     rs1[r] += e1;
        }
    }

    // reduce row sums across the 16 lanes (llo) of each lane-group
    #pragma unroll
    for (int m = 1; m <= 8; m <<= 1) {
        #pragma unroll
        for (int r = 0; r < 4; r++) {
            rs0[r] += __shfl_xor(rs0[r], m, 64);
            rs1[r] += __shfl_xor(rs1[r], m, 64);
        }
    }
    if (llo == 0) {
        #pragma unroll
        for (int r = 0; r < 4; r++) {
            red[wave][lhi * 4 + r]      = rs0[r];
            red[wave][16 + lhi * 4 + r] = rs1[r];
        }
    }
    __syncthreads();

    float inv0[4], inv1[4];
    #pragma unroll
    for (int r = 0; r < 4; r++) {
        float s0 = 0.f, s1 = 0.f;
        #pragma unroll
        for (int wv = 0; wv < 8; wv++) {
            s0 += red[wv][lhi * 4 + r];
            s1 += red[wv][16 + lhi * 4 + r];
        }
        inv0[r] = 1.0f / s0;
        inv1[r] = 1.0f / s1;
    }

    float* qbase = qdist + rowbase * KC;
    #pragma unroll
    for (int ct = 0; ct < 8; ct++) {
        const int col = cb + ct * 16 + llo;
        #pragma unroll
        for (int r = 0; r < 4; r++) {
            qbase[(lhi * 4 + r) * KC + col]        = e[ct][0][r] * inv0[r];
            qbase[(16 + lhi * 4 + r) * KC + col]   = e[ct][1][r] * inv1[r];
        }
    }
}

// ---------------------------------------------------------------------------
// PV kernel: quantized = q [N][1024] @ W [1024][256], bf16 MFMA,
// B-operand read from wtbf [256][1024] (contiguous k per lane).
// Block: 64 rows x 256 cols, 8 waves (2 row-blocks x 4 col-blocks).
// ---------------------------------------------------------------------------
#define BMB 64
#define ALD 40    // 32 + 8 pad (bf16 elems); row stride 80 B

__global__ __launch_bounds__(512, 4) void pv_kernel(
    const float* __restrict__ qdist, const short* __restrict__ wtbf,
    float* __restrict__ quant) {
    __shared__ short as_[BMB * ALD];

    const int t    = threadIdx.x;
    const int wave = t >> 6;
    const int lane = t & 63;
    const int lhi  = lane >> 4, llo = lane & 15;
    const long rowbase = (long)blockIdx.x * BMB;
    const int wrow = (wave >> 2) * 32;   // 0 or 32
    const int wcol = (wave & 3) * 64;    // 0,64,128,192

    f32x4 acc[2][4];
    #pragma unroll
    for (int i = 0; i < 2; i++)
        #pragma unroll
        for (int j = 0; j < 4; j++)
            acc[i][j] = (f32x4){0.f, 0.f, 0.f, 0.f};

    const int srow = t >> 3, sf4 = t & 7;
    const f32x4* qv = (const f32x4*)(qdist + (rowbase + srow) * KC);

    for (int kc = 0; kc < 32; kc++) {
        f32x4 v = qv[kc * 8 + sf4];
        s16x4 sv;
        sv[0] = f2bf(v[0]); sv[1] = f2bf(v[1]); sv[2] = f2bf(v[2]); sv[3] = f2bf(v[3]);
        __syncthreads();                       // previous iter's LDS reads done
        *(s16x4*)(as_ + srow * ALD + sf4 * 4) = sv;
        __syncthreads();                       // tile staged

        bf16x8 a0 = *(const bf16x8*)(as_ + (wrow + llo) * ALD + lhi * 8);
        bf16x8 a1 = *(const bf16x8*)(as_ + (wrow + 16 + llo) * ALD + lhi * 8);
        #pragma unroll
        for (int dt = 0; dt < 4; dt++) {
            const short* wp = wtbf + (size_t)(wcol + dt * 16 + llo) * KC + kc * 32 + lhi * 8;
            bf16x8 b = *(const bf16x8*)wp;
            acc[0][dt] = __builtin_amdgcn_mfma_f32_16x16x32_bf16(a0, b, acc[0][dt], 0, 0, 0);
            acc[1][dt] = __builtin_amdgcn_mfma_f32_16x16x32_bf16(a1, b, acc[1][dt], 0, 0, 0);
        }
    }

    float* obase = quant + rowbase * DD;
    #pragma unroll
    for (int rt = 0; rt < 2; rt++)
        #pragma unroll
        for (int dt = 0; dt < 4; dt++)
            #pragma unroll
            for (int r = 0; r < 4; r++)
                obase[(wrow + rt * 16 + lhi * 4 + r) * DD + wcol + dt * 16 + llo] = acc[rt][dt][r];
}

// ---------------------------------------------------------------------------
extern "C" void kernel_launch(void* const* d_in, const int* in_sizes, int n_in,
                              void* d_out, int out_size, void* d_ws, size_t ws_size,
                              hipStream_t stream) {
    const float* x = (const float*)d_in[0];
    const float* w = (const float*)d_in[1];
    float* out = (float*)d_out;

    const int nrows = in_sizes[0] / DD;          // 65536
    float* quant = out;                          // [nrows][256]
    float* qdist = out + (size_t)nrows * DD;     // [nrows][1024]

    short* wbf  = (short*)d_ws;                  // 1024*256 bf16 = 512 KB
    short* wtbf = wbf + (size_t)KC * DD;         // 256*1024 bf16 = 512 KB
    float* wsq  = (float*)(wtbf + (size_t)DD * KC);  // 1024 fp32

    prep_kernel<<<KC, DD, 0, stream>>>(w, wbf, wtbf, wsq);
    score_kernel<<<nrows / BM, 512, 0, stream>>>(x, wbf, wsq, qdist);
    pv_kernel<<<nrows / BMB, 512, 0, stream>>>(qdist, wtbf, quant);
}

// Round 2
// 273.048 us; speedup vs baseline: 1.4523x; 1.4523x over previous
//
#include <hip/hip_runtime.h>
#include <hip/hip_bf16.h>

#define DD 256
#define KC 1024
#define BM 32
#define XLD 264   // x tile row stride (bf16 elems): 528 B
#define QLD 136   // q tile row stride (bf16 elems): 272 B = 68 dwords (uniform bank tiling)

typedef __attribute__((ext_vector_type(4))) float f32x4;
typedef __attribute__((ext_vector_type(8))) short bf16x8;
typedef __attribute__((ext_vector_type(4))) short s16x4;

static __device__ __forceinline__ short f2bf(float f) {
    union { float f; unsigned u; } v; v.f = f;
    unsigned u = v.u;
    unsigned r = u + 0x7fffu + ((u >> 16) & 1u);
    return (short)(r >> 16);
}

// ---------------------------------------------------------------------------
// prep: W fp32 [1024][256] -> wbf bf16 [1024][256], wtbf bf16 [256][1024],
//       wsq[k] = sum_d W[k][d]^2 / 256
// ---------------------------------------------------------------------------
__global__ void prep_kernel(const float* __restrict__ w, short* __restrict__ wbf,
                            short* __restrict__ wtbf, float* __restrict__ wsq) {
    const int cod = blockIdx.x;
    const int d   = threadIdx.x;           // 256 threads
    float v = w[cod * DD + d];
    short b = f2bf(v);
    wbf[cod * DD + d] = b;
    wtbf[d * KC + cod] = b;
    float s = v * v;
    #pragma unroll
    for (int m = 32; m >= 1; m >>= 1) s += __shfl_xor(s, m, 64);
    __shared__ float ps[4];
    const int wave = threadIdx.x >> 6, lane = threadIdx.x & 63;
    if (lane == 0) ps[wave] = s;
    __syncthreads();
    if (threadIdx.x == 0) {
        wsq[cod] = (ps[0] + ps[1] + ps[2] + ps[3]) * (1.0f / (float)DD);
    }
}

// ---------------------------------------------------------------------------
// Fused kernel: per block 32 rows, 8 waves.
// Phase 2: wave w computes cross for codes [w*128, w*128+128), e = exp(.)
// Phase 3: cross-wave rowsum reduce -> inv
// Phase 4: q = e*inv; write qdist f32 (exact) + q bf16 into per-wave LDS tile
// Phase 5: wave w computes quantized[:, w*32:(w+1)*32] = q @ W over all 1024
//          codes, reading all 8 waves' q tiles from LDS, B from wtbf (L2).
// ---------------------------------------------------------------------------
__global__ __launch_bounds__(512, 4) void fused_kernel(
    const float* __restrict__ x, const short* __restrict__ wbf,
    const short* __restrict__ wtbf, const float* __restrict__ wsq,
    float* __restrict__ qdist, float* __restrict__ quant) {
    __shared__ union {
        short xs[BM * XLD];        // 16,896 B  (phase 1-2)
        short qs[8][BM][QLD];      // 69,632 B  (phase 4-5)
    } u;
    __shared__ float red[8][BM];

    const int t    = threadIdx.x;
    const int wave = t >> 6;
    const int lane = t & 63;
    const int lhi  = lane >> 4, llo = lane & 15;
    const long rowbase = (long)blockIdx.x * BM;

    // ---- phase 1: stage x tile (32 x 256 fp32) -> bf16 LDS ----
    const f32x4* xv = (const f32x4*)(x + rowbase * DD);
    #pragma unroll
    for (int i = 0; i < 4; i++) {
        int f4 = t + i * 512;          // row = f4/64, col4 = f4%64
        f32x4 v = xv[f4];
        int row = f4 >> 6, c4 = f4 & 63;
        s16x4 sv;
        sv[0] = f2bf(v[0]); sv[1] = f2bf(v[1]); sv[2] = f2bf(v[2]); sv[3] = f2bf(v[3]);
        *(s16x4*)(u.xs + row * XLD + c4 * 4) = sv;
    }
    __syncthreads();

    // ---- phase 2: cross + exp for this wave's 128 codes ----
    const int cb = wave * 128;
    float e[8][2][4];
    float rs0[4] = {0.f, 0.f, 0.f, 0.f};
    float rs1[4] = {0.f, 0.f, 0.f, 0.f};

    #pragma unroll
    for (int ct = 0; ct < 8; ct++) {
        const int cod = cb + ct * 16 + llo;
        f32x4 acc0 = {0.f, 0.f, 0.f, 0.f};
        f32x4 acc1 = {0.f, 0.f, 0.f, 0.f};
        const short* wrow = wbf + (size_t)cod * DD + lhi * 8;
        const short* xr0  = u.xs + llo * XLD + lhi * 8;
        const short* xr1  = xr0 + 16 * XLD;
        #pragma unroll
        for (int kk = 0; kk < 8; kk++) {
            bf16x8 bf = *(const bf16x8*)(wrow + kk * 32);
            bf16x8 a0 = *(const bf16x8*)(xr0 + kk * 32);
            bf16x8 a1 = *(const bf16x8*)(xr1 + kk * 32);
            acc0 = __builtin_amdgcn_mfma_f32_16x16x32_bf16(a0, bf, acc0, 0, 0, 0);
            acc1 = __builtin_amdgcn_mfma_f32_16x16x32_bf16(a1, bf, acc1, 0, 0, 0);
        }
        const float ws = wsq[cod];
        #pragma unroll
        for (int r = 0; r < 4; r++) {
            float e0 = __expf(acc0[r] * (1.0f / 128.0f) - ws);
            float e1 = __expf(acc1[r] * (1.0f / 128.0f) - ws);
            e[ct][0][r] = e0; e[ct][1][r] = e1;
            rs0[r] += e0;     rs1[r] += e1;
        }
    }

    // ---- phase 3: rowsum reduce across llo lanes, then across waves ----
    #pragma unroll
    for (int m = 1; m <= 8; m <<= 1) {
        #pragma unroll
        for (int r = 0; r < 4; r++) {
            rs0[r] += __shfl_xor(rs0[r], m, 64);
            rs1[r] += __shfl_xor(rs1[r], m, 64);
        }
    }
    if (llo == 0) {
        #pragma unroll
        for (int r = 0; r < 4; r++) {
            red[wave][lhi * 4 + r]      = rs0[r];
            red[wave][16 + lhi * 4 + r] = rs1[r];
        }
    }
    __syncthreads();   // also guarantees all xs reads are done (qs aliases xs)

    float inv0[4], inv1[4];
    #pragma unroll
    for (int r = 0; r < 4; r++) {
        float s0 = 0.f, s1 = 0.f;
        #pragma unroll
        for (int wv = 0; wv < 8; wv++) {
            s0 += red[wv][lhi * 4 + r];
            s1 += red[wv][16 + lhi * 4 + r];
        }
        inv0[r] = 1.0f / s0;
        inv1[r] = 1.0f / s1;
    }

    // ---- phase 4: normalize; write qdist (f32, exact) + q bf16 to LDS ----
    float* qbase = qdist + rowbase * KC;
    #pragma unroll
    for (int ct = 0; ct < 8; ct++) {
        const int col = ct * 16 + llo;
        #pragma unroll
        for (int r = 0; r < 4; r++) {
            const int r0 = lhi * 4 + r, r1 = 16 + lhi * 4 + r;
            float q0 = e[ct][0][r] * inv0[r];
            float q1 = e[ct][1][r] * inv1[r];
            u.qs[wave][r0][col] = f2bf(q0);
            u.qs[wave][r1][col] = f2bf(q1);
            qbase[r0 * KC + cb + col] = q0;
            qbase[r1 * KC + cb + col] = q1;
        }
    }
    __syncthreads();

    // ---- phase 5: PV — wave owns d-cols [wave*32, wave*32+32) ----
    const int wcol = wave * 32;
    f32x4 acc[2][2];
    #pragma unroll
    for (int i = 0; i < 2; i++)
        #pragma unroll
        for (int j = 0; j < 2; j++)
            acc[i][j] = (f32x4){0.f, 0.f, 0.f, 0.f};

    #pragma unroll 4
    for (int kc = 0; kc < 32; kc++) {
        const int sw = kc >> 2;              // source wave buffer
        const int lc = (kc & 3) * 32;        // local code offset in buffer
        const short* qp = &u.qs[sw][llo][lc + lhi * 8];
        bf16x8 a0 = *(const bf16x8*)qp;
        bf16x8 a1 = *(const bf16x8*)(qp + 16 * QLD);
        #pragma unroll
        for (int cbi = 0; cbi < 2; cbi++) {
            const short* wp = wtbf + (size_t)(wcol + cbi * 16 + llo) * KC + kc * 32 + lhi * 8;
            bf16x8 b = *(const bf16x8*)wp;
            acc[0][cbi] = __builtin_amdgcn_mfma_f32_16x16x32_bf16(a0, b, acc[0][cbi], 0, 0, 0);
            acc[1][cbi] = __builtin_amdgcn_mfma_f32_16x16x32_bf16(a1, b, acc[1][cbi], 0, 0, 0);
        }
    }

    // ---- phase 6: write quantized ----
    float* obase = quant + rowbase * DD;
    #pragma unroll
    for (int rb = 0; rb < 2; rb++)
        #pragma unroll
        for (int cbi = 0; cbi < 2; cbi++)
            #pragma unroll
            for (int r = 0; r < 4; r++)
                obase[(rb * 16 + lhi * 4 + r) * DD + wcol + cbi * 16 + llo] = acc[rb][cbi][r];
}

// ---------------------------------------------------------------------------
extern "C" void kernel_launch(void* const* d_in, const int* in_sizes, int n_in,
                              void* d_out, int out_size, void* d_ws, size_t ws_size,
                              hipStream_t stream) {
    const float* x = (const float*)d_in[0];
    const float* w = (const float*)d_in[1];
    float* out = (float*)d_out;

    const int nrows = in_sizes[0] / DD;          // 65536
    float* quant = out;                          // [nrows][256]
    float* qdist = out + (size_t)nrows * DD;     // [nrows][1024]

    short* wbf  = (short*)d_ws;                  // 1024*256 bf16 = 512 KB
    short* wtbf = wbf + (size_t)KC * DD;         // 256*1024 bf16 = 512 KB
    float* wsq  = (float*)(wtbf + (size_t)DD * KC);  // 1024 fp32

    prep_kernel<<<KC, DD, 0, stream>>>(w, wbf, wtbf, wsq);
    fused_kernel<<<nrows / BM, 512, 0, stream>>>(x, wbf, wtbf, wsq, qdist, quant);
}